// Round 11
// baseline (340.377 us; speedup 1.0000x reference)
//
#include <hip/hip_runtime.h>

// Problem constants: B=1, C=128, H=96, W=128
#define K_TOT 128
#define H_DIM 96
#define W_DIM 128
#define M_TOT (H_DIM * W_DIM)   // 12288
#define N_TOT (H_DIM * W_DIM)   // 12288
#define SCALE 4
#define NEG_INF (-3.402823e38f)

#define KP 384                  // folded K' = 3 x 128 sections
#define NH 24                   // K' halves of 16
#define NH2 12                  // halves per K-split wave
#define SLAB_F16 24576          // 64 rows x 384 k' f16 per slab

typedef _Float16 f16x8 __attribute__((ext_vector_type(8)));
typedef float f32x16 __attribute__((ext_vector_type(16)));

// ---------------------------------------------------------------------------
// Prep: fp32 [K][P] -> f16 triplet in FRAG-MAJOR layout + fused keys-init.
//  x = h + l/64 with h=f16(x), l=f16((x-hf)*64)  (x-hf exact by Sterbenz)
//  k' sections: L: [h | h/64 | l]   R: [h | l | h/64]
//  => dot = h*h' + h*(y-h') + (x-h)*h'  (drop (x-h)(y-h') ~ 2^-22|xy|)
// Frag-major: slab s (64 rows), chunk c = half*128 + op*64 + hi*32 + col:
// 8 f16 at dst[s*24576 + c*8] = exactly lane (hi*32+col)'s MFMA operand bytes.
// ---------------------------------------------------------------------------
__global__ __launch_bounds__(256)
void split_prep_kernel(const float* __restrict__ L, const float* __restrict__ R,
                       _Float16* __restrict__ Ls, _Float16* __restrict__ Rs,
                       unsigned long long* __restrict__ keys) {
    const int t = threadIdx.x;
    if (blockIdx.x >= 384) {            // fused keys init (48 blocks)
        int m = (blockIdx.x - 384) * 256 + t;
        if (m < M_TOT) keys[m] = 0ull;
        return;
    }
    __shared__ __align__(16) _Float16 T[3][64][144];   // planes: 0=h, 1=l, 2=h/64
    const int isR  = blockIdx.x >= 192;
    const int slab = blockIdx.x - (isR ? 192 : 0);     // 0..191
    const int P0   = slab * 64;
    const float* src = isR ? R : L;
    _Float16* dst = isR ? Rs : Ls;

    const int p4 = (t & 15) * 4;
    const int k0 = t >> 4;
#pragma unroll
    for (int it = 0; it < 8; ++it) {
        const int k = k0 + it * 16;
        float4 v = *(const float4*)&src[(size_t)k * M_TOT + P0 + p4];
        float xs[4] = {v.x, v.y, v.z, v.w};
#pragma unroll
        for (int j = 0; j < 4; ++j) {
            _Float16 h = (_Float16)xs[j];
            float hf = (float)h;
            float r = xs[j] - hf;                    // exact
            T[0][p4 + j][k] = h;
            T[1][p4 + j][k] = (_Float16)(r * 64.0f);
            T[2][p4 + j][k] = (_Float16)(hf * 0.015625f);  // h/64 (exact exp shift)
        }
    }
    __syncthreads();
    // 3072 16B-chunks per slab: c = half*128 + op*64 + hi*32 + col
#pragma unroll
    for (int it = 0; it < 12; ++it) {
        const int c    = it * 256 + t;
        const int col  = c & 31;
        const int hi   = (c >> 5) & 1;
        const int op   = (c >> 6) & 1;
        const int half = c >> 7;             // 0..23
        const int sec  = half >> 3;          // 0,1,2
        const int kb   = (half & 7) * 16 + hi * 8;
        const int plane = (sec == 0) ? 0 : (isR ? sec : 3 - sec);
        const int row  = op * 32 + col;
        float4 v = *(const float4*)&T[plane][row][kb];
        *(float4*)&dst[(size_t)slab * SLAB_F16 + (size_t)c * 8] = v;
    }
}

// ---------------------------------------------------------------------------
// Main: 128x128 tile, 8 waves = 4 spatial (2x2 of 64x64) x 2 K'-halves.
// K'-SPLIT: each wave runs only 12 latency-bound iterations (the serial
// chain that bounds r10) over its K'-half; kh=1 waves publish f32 partials
// to LDS (contiguous float4, conflict-free), kh=0 waves add + do argmax.
// Loads stay global->VGPR from the frag-major workspace (no LDS in K-loop),
// depth-2 prefetch, 3 reg buffers, compiler-counted vmcnt. Per-CU waves,
// registers, and in-flight loads identical to r10 -- only the per-block
// serial iteration count halves. setprio(1) around the MFMA quad (m191
// independent-phase regime). 2 blocks/CU (64KB LDS), 16 waves/CU.
// ---------------------------------------------------------------------------
__global__ __launch_bounds__(512, 4)
void mfma_corr_kernel(const _Float16* __restrict__ Ls, const _Float16* __restrict__ Rs,
                      unsigned long long* __restrict__ keys) {
    __shared__ __align__(16) char smem[65536];   // exch 4x16KB; reused for reduce

    const int tid  = threadIdx.x;
    const int lane = tid & 63;
    const int wid  = tid >> 6;      // 0..7
    const int kh   = wid >> 2;      // 0..1 : K'-half
    const int sw   = wid & 3;       // 0..3 : spatial wave
    const int wr   = sw >> 1;       // 0..1 : M 64-row slab
    const int wc   = sw & 1;        // 0..1 : N 64-col slab
    const int col  = lane & 31;
    const int hi   = lane >> 5;
    // supertile: 9216 = 8 XCDs x (96 mt x 12 nt_local); bijective
    const int bid  = blockIdx.x;
    const int xcd  = bid & 7;
    const int b    = bid >> 3;              // 0..1151
    const int mt   = b / 12;                // 0..95 (slow)
    const int nt   = xcd * 12 + b % 12;     // 0..95 (XCD-local slice)
    const int m0   = mt * 128;
    const int n0   = nt * 128;

    const _Float16* pA = Ls + (size_t)(mt * 2 + wr) * SLAB_F16 + kh * (NH2 * 1024) + lane * 8;
    const _Float16* pB = Rs + (size_t)(nt * 2 + wc) * SLAB_F16 + kh * (NH2 * 1024) + lane * 8;

    f32x16 acc[2][2];
#pragma unroll
    for (int mi = 0; mi < 2; ++mi)
#pragma unroll
        for (int ni = 0; ni < 2; ++ni) acc[mi][ni] = (f32x16)(0.0f);

    f16x8 fA[3][2], fB[3][2];
#define LOADH(hh, s) {                                              \
        fA[s][0] = *(const f16x8*)(pA + (hh) * 1024);               \
        fA[s][1] = *(const f16x8*)(pA + (hh) * 1024 + 512);         \
        fB[s][0] = *(const f16x8*)(pB + (hh) * 1024);               \
        fB[s][1] = *(const f16x8*)(pB + (hh) * 1024 + 512);         \
    }
    LOADH(0, 0);
    LOADH(1, 1);
#pragma unroll
    for (int h = 0; h < NH2; ++h) {
        if (h + 2 < NH2) LOADH(h + 2, (h + 2) % 3);     // depth-2 prefetch
        const int s = h % 3;                             // static under unroll
        __builtin_amdgcn_s_setprio(1);
        acc[0][0] = __builtin_amdgcn_mfma_f32_32x32x16_f16(fA[s][0], fB[s][0], acc[0][0], 0, 0, 0);
        acc[0][1] = __builtin_amdgcn_mfma_f32_32x32x16_f16(fA[s][0], fB[s][1], acc[0][1], 0, 0, 0);
        acc[1][0] = __builtin_amdgcn_mfma_f32_32x32x16_f16(fA[s][1], fB[s][0], acc[1][0], 0, 0, 0);
        acc[1][1] = __builtin_amdgcn_mfma_f32_32x32x16_f16(fA[s][1], fB[s][1], acc[1][1], 0, 0, 0);
        __builtin_amdgcn_s_setprio(0);
    }
#undef LOADH

    // --- K'-half combine: kh=1 publishes, kh=0 adds ---
    if (kh == 1) {
        float* ex = (float*)smem + sw * 4096;
#pragma unroll
        for (int mi = 0; mi < 2; ++mi)
#pragma unroll
            for (int ni = 0; ni < 2; ++ni) {
                const int frag = mi * 2 + ni;
#pragma unroll
                for (int q = 0; q < 4; ++q) {
                    float4 v = { acc[mi][ni][q * 4 + 0], acc[mi][ni][q * 4 + 1],
                                 acc[mi][ni][q * 4 + 2], acc[mi][ni][q * 4 + 3] };
                    *(float4*)&ex[frag * 1024 + q * 256 + lane * 4] = v;
                }
            }
    }
    __syncthreads();
    if (kh == 0) {
        const float* ex = (const float*)smem + sw * 4096;
#pragma unroll
        for (int mi = 0; mi < 2; ++mi)
#pragma unroll
            for (int ni = 0; ni < 2; ++ni) {
                const int frag = mi * 2 + ni;
#pragma unroll
                for (int q = 0; q < 4; ++q) {
                    float4 v = *(const float4*)&ex[frag * 1024 + q * 256 + lane * 4];
                    acc[mi][ni][q * 4 + 0] += v.x;
                    acc[mi][ni][q * 4 + 1] += v.y;
                    acc[mi][ni][q * 4 + 2] += v.z;
                    acc[mi][ni][q * 4 + 3] += v.w;
                }
            }
    }
    __syncthreads();   // exch reads done -> region reusable for reduce arrays

    // --- epilogue (kh=0 waves only) ---
    // C/D 32x32 layout: col = lane&31, row = (reg&3) + 8*(reg>>2) + 4*(lane>>5)
    // ni-fold -> lane^16,^8 folds -> LDS [128][17] -> 128-thread row scan
    float* vals = (float*)smem;                    // 8704 B
    int*   idxs = (int*)(smem + 8704);             // 8704 B
    if (kh == 0) {
#pragma unroll
        for (int mi = 0; mi < 2; ++mi) {
#pragma unroll
            for (int reg = 0; reg < 16; ++reg) {
                float best = acc[mi][0][reg];
                int bni = 0;
                if (acc[mi][1][reg] > best) { best = acc[mi][1][reg]; bni = 1; }
                int n = n0 + wc * 64 + bni * 32 + col;
#pragma unroll
                for (int d = 16; d >= 8; d >>= 1) {    // fold cols ^16 then ^8
                    float ov = __shfl_xor(best, d, 64);
                    int   oi = __shfl_xor(n, d, 64);
                    if (ov > best || (ov == best && oi < n)) { best = ov; n = oi; }
                }
                if ((lane & 24) == 0) {
                    const int row = wr * 64 + mi * 32 + (reg & 3) + 8 * (reg >> 2) + 4 * hi;
                    const int c   = wc * 8 + (lane & 7);
                    vals[row * 17 + c] = best;
                    idxs[row * 17 + c] = n;
                }
            }
        }
    }
    __syncthreads();
    if (tid < 128) {
        float bv = vals[tid * 17 + 0]; int bi = idxs[tid * 17 + 0];
#pragma unroll
        for (int c = 1; c < 16; ++c) {
            float v = vals[tid * 17 + c]; int ix = idxs[tid * 17 + c];
            if (v > bv || (v == bv && ix < bi)) { bv = v; bi = ix; }
        }
        unsigned vb = __float_as_uint(bv);
        vb = (vb & 0x80000000u) ? ~vb : (vb | 0x80000000u);
        unsigned long long key = ((unsigned long long)vb << 32) | (unsigned)(~bi);
        atomicMax(&keys[m0 + tid], key);
    }
}

// decode keys -> flow + cost
__global__ void finalize_keys_kernel(const unsigned long long* __restrict__ keys,
                                     float* __restrict__ out) {
    int m = blockIdx.x * blockDim.x + threadIdx.x;
    if (m >= M_TOT) return;
    unsigned long long key = keys[m];
    unsigned hi = (unsigned)(key >> 32);
    unsigned bits = (hi & 0x80000000u) ? (hi & 0x7fffffffu) : ~hi;
    float v = __uint_as_float(bits);
    int idx = (int)(~(unsigned)(key & 0xffffffffu));
    int h = m / W_DIM, w = m % W_DIM;
    int i = idx / W_DIM, j = idx % W_DIM;
    out[m * 2 + 0] = (float)(w - SCALE * j);
    out[m * 2 + 1] = (float)(h - SCALE * i);
    out[2 * M_TOT + m] = v;
}

// ---------------------------------------------------------------------------
// Fallback fp32 VALU path in case ws_size is too small.
// ---------------------------------------------------------------------------
#define BM 128
#define BN 128
#define KB 32
__global__ __launch_bounds__(256)
void corr_argmax_kernel(const float* __restrict__ L, const float* __restrict__ R,
                        float* __restrict__ pbest, int* __restrict__ pidx,
                        int nsplit) {
    __shared__ float As[KB][BM];
    __shared__ float Bs[KB][BN];
    const int tid = threadIdx.x;
    const int mtiles = M_TOT / BM;
    const int mt = blockIdx.x % mtiles;
    const int s  = blockIdx.x / mtiles;
    const int m0 = mt * BM;
    const int ns = N_TOT / nsplit;
    const int ntiles = ns / BN;
    const int tx = tid & 15;
    const int ty = tid >> 4;
    float rbest[8]; int ridx[8];
#pragma unroll
    for (int i = 0; i < 8; ++i) { rbest[i] = NEG_INF; ridx[i] = 0; }
    for (int nt = 0; nt < ntiles; ++nt) {
        const int n0 = s * ns + nt * BN;
        float acc[8][8];
#pragma unroll
        for (int i = 0; i < 8; ++i)
#pragma unroll
            for (int j = 0; j < 8; ++j) acc[i][j] = 0.f;
        for (int kb = 0; kb < K_TOT; kb += KB) {
            __syncthreads();
#pragma unroll
            for (int r = 0; r < 4; ++r) {
                int f  = tid + 256 * r;
                int kk = f >> 5;
                int c4 = f & 31;
                float4 va = *reinterpret_cast<const float4*>(&L[(size_t)(kb + kk) * M_TOT + m0 + c4 * 4]);
                *reinterpret_cast<float4*>(&As[kk][c4 * 4]) = va;
                float4 vb = *reinterpret_cast<const float4*>(&R[(size_t)(kb + kk) * N_TOT + n0 + c4 * 4]);
                *reinterpret_cast<float4*>(&Bs[kk][c4 * 4]) = vb;
            }
            __syncthreads();
#pragma unroll 4
            for (int kk = 0; kk < KB; ++kk) {
                float4 a0 = *reinterpret_cast<const float4*>(&As[kk][ty * 4]);
                float4 a1 = *reinterpret_cast<const float4*>(&As[kk][64 + ty * 4]);
                float4 b0 = *reinterpret_cast<const float4*>(&Bs[kk][tx * 4]);
                float4 b1 = *reinterpret_cast<const float4*>(&Bs[kk][64 + tx * 4]);
                float a[8] = {a0.x, a0.y, a0.z, a0.w, a1.x, a1.y, a1.z, a1.w};
                float b[8] = {b0.x, b0.y, b0.z, b0.w, b1.x, b1.y, b1.z, b1.w};
#pragma unroll
                for (int i = 0; i < 8; ++i)
#pragma unroll
                    for (int j = 0; j < 8; ++j)
                        acc[i][j] = fmaf(a[i], b[j], acc[i][j]);
            }
        }
#pragma unroll
        for (int i = 0; i < 8; ++i)
#pragma unroll
            for (int jh = 0; jh < 2; ++jh)
#pragma unroll
                for (int jj = 0; jj < 4; ++jj) {
                    int n = n0 + jh * 64 + tx * 4 + jj;
                    float v = acc[i][jh * 4 + jj];
                    if (v > rbest[i]) { rbest[i] = v; ridx[i] = n; }
                }
    }
    __syncthreads();
    float (*redv)[BM] = reinterpret_cast<float(*)[BM]>(&As[0][0]);
    int   (*redi)[BM] = reinterpret_cast<int  (*)[BM]>(&Bs[0][0]);
#pragma unroll
    for (int i = 0; i < 8; ++i) {
        int row = (i >> 2) * 64 + ty * 4 + (i & 3);
        redv[tx][row] = rbest[i];
        redi[tx][row] = ridx[i];
    }
    __syncthreads();
    if (tid < BM) {
        float bv = NEG_INF; int bi = 0x7fffffff;
        for (int t = 0; t < 16; ++t) {
            float v  = redv[t][tid];
            int   ix = redi[t][tid];
            if (v > bv || (v == bv && ix < bi)) { bv = v; bi = ix; }
        }
        pbest[(size_t)s * M_TOT + m0 + tid] = bv;
        pidx [(size_t)s * M_TOT + m0 + tid] = bi;
    }
}

__global__ void finalize_parts_kernel(const float* __restrict__ pbest,
                                      const int* __restrict__ pidx,
                                      float* __restrict__ out, int nsplit) {
    int m = blockIdx.x * blockDim.x + threadIdx.x;
    if (m >= M_TOT) return;
    float bv = NEG_INF; int bi = 0x7fffffff;
    for (int s = 0; s < nsplit; ++s) {
        float v  = pbest[(size_t)s * M_TOT + m];
        int   ix = pidx [(size_t)s * M_TOT + m];
        if (v > bv || (v == bv && ix < bi)) { bv = v; bi = ix; }
    }
    int h = m / W_DIM, w = m % W_DIM;
    int i = bi / W_DIM, j = bi % W_DIM;
    out[m * 2 + 0] = (float)(w - SCALE * j);
    out[m * 2 + 1] = (float)(h - SCALE * i);
    out[2 * M_TOT + m] = bv;
}

extern "C" void kernel_launch(void* const* d_in, const int* in_sizes, int n_in,
                              void* d_out, int out_size, void* d_ws, size_t ws_size,
                              hipStream_t stream) {
    const float* L = (const float*)d_in[0];
    const float* R = (const float*)d_in[1];
    float* out = (float*)d_out;

    const size_t PKbytes = (size_t)M_TOT * KP * sizeof(_Float16);   // 9.44 MB
    const size_t need = 2 * PKbytes + (size_t)M_TOT * 8;            // ~19 MB
    if (ws_size >= need) {
        _Float16* Ls = (_Float16*)d_ws;
        _Float16* Rs = (_Float16*)((char*)d_ws + PKbytes);
        unsigned long long* keys = (unsigned long long*)((char*)d_ws + 2 * PKbytes);
        split_prep_kernel<<<dim3(432), dim3(256), 0, stream>>>(L, R, Ls, Rs, keys);
        mfma_corr_kernel<<<dim3((M_TOT / 128) * (N_TOT / 128)), dim3(512), 0, stream>>>(Ls, Rs, keys);
        finalize_keys_kernel<<<dim3(48), dim3(256), 0, stream>>>(keys, out);
    } else {
        int nsplit = 8;
        while (nsplit > 1 && (size_t)nsplit * M_TOT * 8 > ws_size) nsplit >>= 1;
        float* pbest = (float*)d_ws;
        int*   pidx  = (int*)((char*)d_ws + (size_t)nsplit * M_TOT * sizeof(float));
        corr_argmax_kernel<<<dim3((M_TOT / BM) * nsplit), dim3(256), 0, stream>>>(L, R, pbest, pidx, nsplit);
        finalize_parts_kernel<<<dim3((M_TOT + 255) / 256), dim3(256), 0, stream>>>(pbest, pidx, out, nsplit);
    }
}

// Round 12
// 224.979 us; speedup vs baseline: 1.5129x; 1.5129x over previous
//
#include <hip/hip_runtime.h>

// Problem constants: B=1, C=128, H=96, W=128
#define K_TOT 128
#define H_DIM 96
#define W_DIM 128
#define M_TOT (H_DIM * W_DIM)   // 12288
#define N_TOT (H_DIM * W_DIM)   // 12288
#define SCALE 4
#define NEG_INF (-3.402823e38f)

#define KP 384                  // folded K' = 3 x 128 sections
#define NH 24                   // K' halves of 16
#define SLAB_F16 24576          // 64 rows x 384 k' f16 per slab

typedef _Float16 f16x8 __attribute__((ext_vector_type(8)));
typedef float f32x16 __attribute__((ext_vector_type(16)));

// ---------------------------------------------------------------------------
// Prep: fp32 [K][P] -> f16 triplet in FRAG-MAJOR layout + fused keys-init.
//  x = h + l/64 with h=f16(x), l=f16((x-hf)*64)  (x-hf exact by Sterbenz)
//  k' sections: L: [h | h/64 | l]   R: [h | l | h/64]
//  => dot = h*h' + h*(y-h') + (x-h)*h'  (drop (x-h)(y-h') ~ 2^-22|xy|)
// Frag-major: slab s (64 rows), chunk c = half*128 + op*64 + hi*32 + col:
// 8 f16 at dst[s*24576 + c*8] = exactly lane (hi*32+col)'s MFMA operand bytes.
//
// r12: 4x finer decomposition than r10's 384-block version (which was
// occupancy-bound at 1.5 blocks/CU and cost ~45-70us). 1536 blocks: each
// handles one (slab, k-quarter): reads 32k x 64p floats, converts its 3
// planes (no duplicated work), writes its 768 16B chunks (halves with
// half&7 in {2q, 2q+1} across the 3 sections; klocal = jj*16+hi*8).
// ---------------------------------------------------------------------------
__global__ __launch_bounds__(256)
void split_prep_kernel(const float* __restrict__ L, const float* __restrict__ R,
                       _Float16* __restrict__ Ls, _Float16* __restrict__ Rs,
                       unsigned long long* __restrict__ keys) {
    const int t = threadIdx.x;
    if (blockIdx.x >= 1536) {           // fused keys init (48 blocks)
        int m = (blockIdx.x - 1536) * 256 + t;
        if (m < M_TOT) keys[m] = 0ull;
        return;
    }
    __shared__ __align__(16) _Float16 T[3][64][40];   // planes: 0=h, 1=l, 2=h/64
    const int isR  = blockIdx.x >= 768;
    const int bb   = blockIdx.x - (isR ? 768 : 0);    // 0..767
    const int slab = bb >> 2;                         // 0..191
    const int q    = bb & 3;                          // k-quarter
    const int P0   = slab * 64;
    const int kq   = q * 32;
    const float* src = isR ? R : L;
    _Float16* dst = isR ? Rs : Ls;

    const int p4 = (t & 15) * 4;
    const int k0 = t >> 4;              // 0..15
#pragma unroll
    for (int it = 0; it < 2; ++it) {
        const int kl = k0 + it * 16;    // local k 0..31
        float4 v = *(const float4*)&src[(size_t)(kq + kl) * M_TOT + P0 + p4];
        float xs[4] = {v.x, v.y, v.z, v.w};
#pragma unroll
        for (int j = 0; j < 4; ++j) {
            _Float16 h = (_Float16)xs[j];
            float hf = (float)h;
            float r = xs[j] - hf;                    // exact
            T[0][p4 + j][kl] = h;
            T[1][p4 + j][kl] = (_Float16)(r * 64.0f);
            T[2][p4 + j][kl] = (_Float16)(hf * 0.015625f);  // h/64 (exact exp shift)
        }
    }
    __syncthreads();
    // 768 16B chunks for this (slab, quarter): u = sec*256 + jj*128 + op*64 + hi*32 + col
#pragma unroll
    for (int it = 0; it < 3; ++it) {
        const int u   = it * 256 + t;   // 0..767
        const int col = u & 31;
        const int hi  = (u >> 5) & 1;
        const int op  = (u >> 6) & 1;
        const int jj  = (u >> 7) & 1;
        const int sec = u >> 8;         // 0..2
        const int half   = sec * 8 + 2 * q + jj;
        const int c      = half * 128 + op * 64 + hi * 32 + col;
        const int klocal = jj * 16 + hi * 8;     // within our 32-k window
        const int plane  = (sec == 0) ? 0 : (isR ? sec : 3 - sec);
        const int row    = op * 32 + col;
        float4 v = *(const float4*)&T[plane][row][klocal];   // 80B row stride: 16B-aligned
        *(float4*)&dst[(size_t)slab * SLAB_F16 + (size_t)c * 8] = v;
    }
}

// ---------------------------------------------------------------------------
// Main (reverted to r10, the best-measured configuration, 160us):
// 128x128 tile, 4 waves (2x2), wave-tile 64x64, mfma_f32_32x32x16_f16.
// NO LDS / NO barriers in the K loop: fragments load directly global->VGPR
// from the frag-major workspace (coalesced 1024B per wave-frag), register
// triple-buffer with depth-2 prefetch (static %3 indices under full unroll);
// the compiler inserts the counted vmcnt before first use. Reuse lives in
// L2: XCD supertile keeps each XCD's 1.15 MB B slice resident.
// 16 waves/CU (launch_bounds(256,4)): 64 VGPR + 64 AGPR = 128/wave budget.
// setprio(1) around the MFMA quad (independent-phase regime).
// ---------------------------------------------------------------------------
__global__ __launch_bounds__(256, 4)
void mfma_corr_kernel(const _Float16* __restrict__ Ls, const _Float16* __restrict__ Rs,
                      unsigned long long* __restrict__ keys) {
    __shared__ float vals[128 * 17];
    __shared__ int   idxs[128 * 17];

    const int tid  = threadIdx.x;
    const int lane = tid & 63;
    const int wid  = tid >> 6;      // 0..3
    const int wr   = wid >> 1;      // 0..1 : M 64-row slab
    const int wc   = wid & 1;       // 0..1 : N 64-col slab
    const int col  = lane & 31;
    const int hi   = lane >> 5;
    // supertile: 9216 = 8 XCDs x (96 mt x 12 nt_local); bijective
    const int bid  = blockIdx.x;
    const int xcd  = bid & 7;
    const int b    = bid >> 3;              // 0..1151
    const int mt   = b / 12;                // 0..95 (slow)
    const int nt   = xcd * 12 + b % 12;     // 0..95 (XCD-local slice)
    const int m0   = mt * 128;
    const int n0   = nt * 128;

    const _Float16* pA = Ls + (size_t)(mt * 2 + wr) * SLAB_F16 + lane * 8;
    const _Float16* pB = Rs + (size_t)(nt * 2 + wc) * SLAB_F16 + lane * 8;

    f32x16 acc[2][2];
#pragma unroll
    for (int mi = 0; mi < 2; ++mi)
#pragma unroll
        for (int ni = 0; ni < 2; ++ni) acc[mi][ni] = (f32x16)(0.0f);

    f16x8 fA[3][2], fB[3][2];
#define LOADH(hh, s) {                                              \
        fA[s][0] = *(const f16x8*)(pA + (hh) * 1024);               \
        fA[s][1] = *(const f16x8*)(pA + (hh) * 1024 + 512);         \
        fB[s][0] = *(const f16x8*)(pB + (hh) * 1024);               \
        fB[s][1] = *(const f16x8*)(pB + (hh) * 1024 + 512);         \
    }
    LOADH(0, 0);
    LOADH(1, 1);
#pragma unroll
    for (int h = 0; h < NH; ++h) {
        if (h + 2 < NH) LOADH(h + 2, (h + 2) % 3);      // depth-2 prefetch
        const int s = h % 3;                             // static under unroll
        __builtin_amdgcn_s_setprio(1);
        acc[0][0] = __builtin_amdgcn_mfma_f32_32x32x16_f16(fA[s][0], fB[s][0], acc[0][0], 0, 0, 0);
        acc[0][1] = __builtin_amdgcn_mfma_f32_32x32x16_f16(fA[s][0], fB[s][1], acc[0][1], 0, 0, 0);
        acc[1][0] = __builtin_amdgcn_mfma_f32_32x32x16_f16(fA[s][1], fB[s][0], acc[1][0], 0, 0, 0);
        acc[1][1] = __builtin_amdgcn_mfma_f32_32x32x16_f16(fA[s][1], fB[s][1], acc[1][1], 0, 0, 0);
        __builtin_amdgcn_s_setprio(0);
    }
#undef LOADH

    // --- epilogue ---
    // C/D 32x32 layout: col = lane&31, row = (reg&3) + 8*(reg>>2) + 4*(lane>>5)
    // ni-fold -> lane^16,^8 folds -> LDS [128][17] -> 128-thread row scan
#pragma unroll
    for (int mi = 0; mi < 2; ++mi) {
#pragma unroll
        for (int reg = 0; reg < 16; ++reg) {
            float best = acc[mi][0][reg];
            int bni = 0;
            if (acc[mi][1][reg] > best) { best = acc[mi][1][reg]; bni = 1; }
            int n = n0 + wc * 64 + bni * 32 + col;
#pragma unroll
            for (int d = 16; d >= 8; d >>= 1) {    // fold cols ^16 then ^8
                float ov = __shfl_xor(best, d, 64);
                int   oi = __shfl_xor(n, d, 64);
                if (ov > best || (ov == best && oi < n)) { best = ov; n = oi; }
            }
            if ((lane & 24) == 0) {
                const int row = wr * 64 + mi * 32 + (reg & 3) + 8 * (reg >> 2) + 4 * hi;
                const int c   = wc * 8 + (lane & 7);
                vals[row * 17 + c] = best;
                idxs[row * 17 + c] = n;
            }
        }
    }
    __syncthreads();
    if (tid < 128) {
        float bv = vals[tid * 17 + 0]; int bi = idxs[tid * 17 + 0];
#pragma unroll
        for (int c = 1; c < 16; ++c) {
            float v = vals[tid * 17 + c]; int ix = idxs[tid * 17 + c];
            if (v > bv || (v == bv && ix < bi)) { bv = v; bi = ix; }
        }
        unsigned vb = __float_as_uint(bv);
        vb = (vb & 0x80000000u) ? ~vb : (vb | 0x80000000u);
        unsigned long long key = ((unsigned long long)vb << 32) | (unsigned)(~bi);
        atomicMax(&keys[m0 + tid], key);
    }
}

// decode keys -> flow + cost
__global__ void finalize_keys_kernel(const unsigned long long* __restrict__ keys,
                                     float* __restrict__ out) {
    int m = blockIdx.x * blockDim.x + threadIdx.x;
    if (m >= M_TOT) return;
    unsigned long long key = keys[m];
    unsigned hi = (unsigned)(key >> 32);
    unsigned bits = (hi & 0x80000000u) ? (hi & 0x7fffffffu) : ~hi;
    float v = __uint_as_float(bits);
    int idx = (int)(~(unsigned)(key & 0xffffffffu));
    int h = m / W_DIM, w = m % W_DIM;
    int i = idx / W_DIM, j = idx % W_DIM;
    out[m * 2 + 0] = (float)(w - SCALE * j);
    out[m * 2 + 1] = (float)(h - SCALE * i);
    out[2 * M_TOT + m] = v;
}

// ---------------------------------------------------------------------------
// Fallback fp32 VALU path in case ws_size is too small.
// ---------------------------------------------------------------------------
#define BM 128
#define BN 128
#define KB 32
__global__ __launch_bounds__(256)
void corr_argmax_kernel(const float* __restrict__ L, const float* __restrict__ R,
                        float* __restrict__ pbest, int* __restrict__ pidx,
                        int nsplit) {
    __shared__ float As[KB][BM];
    __shared__ float Bs[KB][BN];
    const int tid = threadIdx.x;
    const int mtiles = M_TOT / BM;
    const int mt = blockIdx.x % mtiles;
    const int s  = blockIdx.x / mtiles;
    const int m0 = mt * BM;
    const int ns = N_TOT / nsplit;
    const int ntiles = ns / BN;
    const int tx = tid & 15;
    const int ty = tid >> 4;
    float rbest[8]; int ridx[8];
#pragma unroll
    for (int i = 0; i < 8; ++i) { rbest[i] = NEG_INF; ridx[i] = 0; }
    for (int nt = 0; nt < ntiles; ++nt) {
        const int n0 = s * ns + nt * BN;
        float acc[8][8];
#pragma unroll
        for (int i = 0; i < 8; ++i)
#pragma unroll
            for (int j = 0; j < 8; ++j) acc[i][j] = 0.f;
        for (int kb = 0; kb < K_TOT; kb += KB) {
            __syncthreads();
#pragma unroll
            for (int r = 0; r < 4; ++r) {
                int f  = tid + 256 * r;
                int kk = f >> 5;
                int c4 = f & 31;
                float4 va = *reinterpret_cast<const float4*>(&L[(size_t)(kb + kk) * M_TOT + m0 + c4 * 4]);
                *reinterpret_cast<float4*>(&As[kk][c4 * 4]) = va;
                float4 vb = *reinterpret_cast<const float4*>(&R[(size_t)(kb + kk) * N_TOT + n0 + c4 * 4]);
                *reinterpret_cast<float4*>(&Bs[kk][c4 * 4]) = vb;
            }
            __syncthreads();
#pragma unroll 4
            for (int kk = 0; kk < KB; ++kk) {
                float4 a0 = *reinterpret_cast<const float4*>(&As[kk][ty * 4]);
                float4 a1 = *reinterpret_cast<const float4*>(&As[kk][64 + ty * 4]);
                float4 b0 = *reinterpret_cast<const float4*>(&Bs[kk][tx * 4]);
                float4 b1 = *reinterpret_cast<const float4*>(&Bs[kk][64 + tx * 4]);
                float a[8] = {a0.x, a0.y, a0.z, a0.w, a1.x, a1.y, a1.z, a1.w};
                float b[8] = {b0.x, b0.y, b0.z, b0.w, b1.x, b1.y, b1.z, b1.w};
#pragma unroll
                for (int i = 0; i < 8; ++i)
#pragma unroll
                    for (int j = 0; j < 8; ++j)
                        acc[i][j] = fmaf(a[i], b[j], acc[i][j]);
            }
        }
#pragma unroll
        for (int i = 0; i < 8; ++i)
#pragma unroll
            for (int jh = 0; jh < 2; ++jh)
#pragma unroll
                for (int jj = 0; jj < 4; ++jj) {
                    int n = n0 + jh * 64 + tx * 4 + jj;
                    float v = acc[i][jh * 4 + jj];
                    if (v > rbest[i]) { rbest[i] = v; ridx[i] = n; }
                }
    }
    __syncthreads();
    float (*redv)[BM] = reinterpret_cast<float(*)[BM]>(&As[0][0]);
    int   (*redi)[BM] = reinterpret_cast<int  (*)[BM]>(&Bs[0][0]);
#pragma unroll
    for (int i = 0; i < 8; ++i) {
        int row = (i >> 2) * 64 + ty * 4 + (i & 3);
        redv[tx][row] = rbest[i];
        redi[tx][row] = ridx[i];
    }
    __syncthreads();
    if (tid < BM) {
        float bv = NEG_INF; int bi = 0x7fffffff;
        for (int t = 0; t < 16; ++t) {
            float v  = redv[t][tid];
            int   ix = redi[t][tid];
            if (v > bv || (v == bv && ix < bi)) { bv = v; bi = ix; }
        }
        pbest[(size_t)s * M_TOT + m0 + tid] = bv;
        pidx [(size_t)s * M_TOT + m0 + tid] = bi;
    }
}

__global__ void finalize_parts_kernel(const float* __restrict__ pbest,
                                      const int* __restrict__ pidx,
                                      float* __restrict__ out, int nsplit) {
    int m = blockIdx.x * blockDim.x + threadIdx.x;
    if (m >= M_TOT) return;
    float bv = NEG_INF; int bi = 0x7fffffff;
    for (int s = 0; s < nsplit; ++s) {
        float v  = pbest[(size_t)s * M_TOT + m];
        int   ix = pidx [(size_t)s * M_TOT + m];
        if (v > bv || (v == bv && ix < bi)) { bv = v; bi = ix; }
    }
    int h = m / W_DIM, w = m % W_DIM;
    int i = bi / W_DIM, j = bi % W_DIM;
    out[m * 2 + 0] = (float)(w - SCALE * j);
    out[m * 2 + 1] = (float)(h - SCALE * i);
    out[2 * M_TOT + m] = bv;
}

extern "C" void kernel_launch(void* const* d_in, const int* in_sizes, int n_in,
                              void* d_out, int out_size, void* d_ws, size_t ws_size,
                              hipStream_t stream) {
    const float* L = (const float*)d_in[0];
    const float* R = (const float*)d_in[1];
    float* out = (float*)d_out;

    const size_t PKbytes = (size_t)M_TOT * KP * sizeof(_Float16);   // 9.44 MB
    const size_t need = 2 * PKbytes + (size_t)M_TOT * 8;            // ~19 MB
    if (ws_size >= need) {
        _Float16* Ls = (_Float16*)d_ws;
        _Float16* Rs = (_Float16*)((char*)d_ws + PKbytes);
        unsigned long long* keys = (unsigned long long*)((char*)d_ws + 2 * PKbytes);
        split_prep_kernel<<<dim3(1584), dim3(256), 0, stream>>>(L, R, Ls, Rs, keys);
        mfma_corr_kernel<<<dim3((M_TOT / 128) * (N_TOT / 128)), dim3(256), 0, stream>>>(Ls, Rs, keys);
        finalize_keys_kernel<<<dim3(48), dim3(256), 0, stream>>>(keys, out);
    } else {
        int nsplit = 8;
        while (nsplit > 1 && (size_t)nsplit * M_TOT * 8 > ws_size) nsplit >>= 1;
        float* pbest = (float*)d_ws;
        int*   pidx  = (int*)((char*)d_ws + (size_t)nsplit * M_TOT * sizeof(float));
        corr_argmax_kernel<<<dim3((M_TOT / BM) * nsplit), dim3(256), 0, stream>>>(L, R, pbest, pidx, nsplit);
        finalize_parts_kernel<<<dim3((M_TOT + 255) / 256), dim3(256), 0, stream>>>(pbest, pidx, out, nsplit);
    }
}